// Round 12
// baseline (137.431 us; speedup 1.0000x reference)
//
#include <hip/hip_runtime.h>
#include <hip/hip_bf16.h>
#include <math.h>

// Problem constants (reference: B=64, N=512, K=32, D=64)
#define BB 64
#define NN 512
#define KK 32
#define DD 64
#define BN (BB*NN)          // 32768
#define EPSC 1e-5f
#define NEG_SLOPE 0.2f
#define NEG_INF_A (-1e9f)

typedef unsigned long long ull;

// Lessons carried: (R1) f32 inputs, not bf16. (R5) per-lane row loads from
// global are uncoalesced -> stage via LDS. (R6) lane*16+q LDS reads are
// 16-way bank-conflicted -> XOR swizzle slot = q ^ (row&15). (R7) never put
// __shfl under divergent control flow. (R9) don't fuse away tiling reuse.
// (R11) k3 gathers are already L2-hit; it is issue-bound -> cut DS ops.

// ---------------------------------------------------------------------------
// KA: cos keys = order-preserving bits of (emb@emb^T)*rsqrt*rsqrt.
// Tile 16 rows x 64 cols; grid 32x8 = 256 blocks. B-tile XOR-swizzled in LDS.
// ---------------------------------------------------------------------------
__global__ void kA_cos(const float* __restrict__ emb, ull* __restrict__ keys) {
    __shared__ float4 As[256];       // 16 A-rows (4 KiB)
    __shared__ float4 Bs[1024];      // 64 B-rows (16 KiB), XOR-swizzled
    __shared__ float rsA[16];
    const int t = threadIdx.x;
    const int lane = t & 63;
    const int wave = t >> 6;
    const int bi = blockIdx.x >> 3;          // row tile (16 rows)
    const int c0 = (blockIdx.x & 7) * 64;    // col tile (64 rows)
    const float4* emb4 = (const float4*)emb;

    As[t] = emb4[bi*256 + t];                        // coalesced
    #pragma unroll
    for (int p = 0; p < 4; ++p) {                    // swizzled stage of B tile
        const int idx = t + 256*p;
        const int r = idx >> 4, q = idx & 15;
        Bs[(r<<4) | (q ^ (r & 15))] = emb4[c0*16 + idx];
    }
    __syncthreads();

    // wave 0: A-row inverse norms (lane = r*4+qq)
    if (wave == 0) {
        const int r = lane >> 2, qq = lane & 3;
        float ss = 0.f;
        #pragma unroll
        for (int m = 0; m < 4; ++m) {
            const float4 a = As[r*16 + qq*4 + m];
            ss += a.x*a.x + a.y*a.y + a.z*a.z + a.w*a.w;
        }
        ss += __shfl_xor(ss, 1);
        ss += __shfl_xor(ss, 2);
        if (qq == 0) rsA[r] = rsqrtf(ss);
    }

    // per-lane B-row fragment via swizzled ds_read_b128 + own norm
    float4 Wr[16];
    float ssW = 0.f;
    #pragma unroll
    for (int q = 0; q < 16; ++q) {
        Wr[q] = Bs[(lane<<4) | (q ^ (lane & 15))];
        ssW += Wr[q].x*Wr[q].x + Wr[q].y*Wr[q].y + Wr[q].z*Wr[q].z + Wr[q].w*Wr[q].w;
    }
    const float rsW = rsqrtf(ssW);
    __syncthreads();                         // rsA ready

    #pragma unroll
    for (int r = 0; r < 4; ++r) {
        const int jr = wave*4 + r;
        float acc = 0.f;
        #pragma unroll
        for (int q = 0; q < 16; ++q) {
            const float4 a = As[jr*16 + q];  // wave-uniform -> LDS broadcast
            const float4 w = Wr[q];
            acc += a.x*w.x + a.y*w.y + a.z*w.z + a.w*w.w;
        }
        const float c = acc * rsA[jr] * rsW;
        const int row = bi*16 + jr;
        const int col = c0 + lane;
        unsigned int u = __float_as_uint(c);
        u = (u & 0x80000000u) ? ~u : (u | 0x80000000u);  // order-preserving bits
        keys[row*NN + col] = ((ull)u << 16) | (ull)(NN - 1 - col);
    }
}

// ---------------------------------------------------------------------------
// KB: rank selection (block=row, thread=j) + BN fold (blk 0). R12: key scan
// as ulonglong2 pairs (ds_read_b128 -> half the DS issue). Keys unique ->
// rank = #{key > mine}; position rank = exact lax.top_k order.
// ---------------------------------------------------------------------------
__global__ void kB_rank(const ull* __restrict__ keys,
                        const float* __restrict__ gnn_bias,
                        const float* __restrict__ g1, const float* __restrict__ b1,
                        const float* __restrict__ m1, const float* __restrict__ v1,
                        const float* __restrict__ go, const float* __restrict__ bo,
                        const float* __restrict__ mo, const float* __restrict__ vo,
                        int* __restrict__ topk, float* __restrict__ epi) {
    __shared__ ull ks[NN];
    const int i = blockIdx.x;
    const int t = threadIdx.x;               // 512 threads
    ks[t] = keys[i*NN + t];

    if (i == 0 && t >= 64 && t < 64 + DD) {  // block 0: fold BN constants
        const int d = t - 64;
        float s1 = g1[d] / sqrtf(v1[d] + EPSC);
        float B1 = (gnn_bias[d] - m1[d]) * s1 + b1[d];
        float so = go[d] / sqrtf(vo[d] + EPSC);
        float Bo = bo[d] - mo[d] * so;
        epi[d] = s1; epi[DD + d] = B1; epi[2*DD + d] = so; epi[3*DD + d] = Bo;
    }
    __syncthreads();
    const ull mykey = ks[t];
    const ulonglong2* ks2 = (const ulonglong2*)ks;
    int rank = 0;
    #pragma unroll 8
    for (int kk = 0; kk < NN/2; ++kk) {
        const ulonglong2 p = ks2[kk];        // ds_read_b128, wave-uniform
        rank += (p.x > mykey) ? 1 : 0;
        rank += (p.y > mykey) ? 1 : 0;
    }
    if (rank < KK) topk[i*KK + rank] = t;
}

// ---------------------------------------------------------------------------
// K2: xl = x @ lin_W^T + si/sj (ei/ej folded inline via emb row loads --
// linearity lets them share the existing butterflies). 32 rows/block,
// XCD-aligned row mapping kept from R11.
// ---------------------------------------------------------------------------
__global__ void k2_lin(const float* __restrict__ data,
                       const float* __restrict__ linW,
                       const float* __restrict__ emb,
                       const float* __restrict__ att_i, const float* __restrict__ att_j,
                       const float* __restrict__ att_em_i,
                       const float* __restrict__ att_em_j,
                       float* __restrict__ xl, float* __restrict__ si,
                       float* __restrict__ sj) {
    __shared__ float4 Ws[1024];         // full W, 16 KiB, XOR-swizzled
    __shared__ float4 xs[512];          // 32 rows x 16 float4 = 8 KiB
    const int t = threadIdx.x;
    const int lane = t & 63;
    const int wave = t >> 6;
    const float4* W4 = (const float4*)linW;

    // XCD-aligned mapping: batch = xcd + 8*(j>>4); 16 sub-blocks per batch.
    const int bid = blockIdx.x;          // 0..1023
    const int xcd = bid & 7;
    const int j   = bid >> 3;            // 0..127
    const int batch = xcd + 8 * (j >> 4);
    const int sub   = j & 15;
    const int row0  = batch * NN + sub * 32;   // 32 rows, all in batch `batch`

    #pragma unroll
    for (int p = 0; p < 4; ++p) {       // swizzled full-W stage (coalesced)
        const int idx = t + 256*p;
        const int r = idx >> 4, q = idx & 15;
        Ws[(r<<4) | (q ^ (r & 15))] = W4[idx];
    }
    xs[t]       = ((const float4*)data)[row0*16 + t];
    xs[t + 256] = ((const float4*)data)[row0*16 + t + 256];
    __syncthreads();

    float4 Wr[16];                      // W[lane][0..63], swizzled read
    #pragma unroll
    for (int q = 0; q < 16; ++q) Wr[q] = Ws[(lane<<4) | (q ^ (lane & 15))];

    const int r0 = wave * 8;            // 8 rows per wave
    float acc[8] = {0.f, 0.f, 0.f, 0.f, 0.f, 0.f, 0.f, 0.f};
    #pragma unroll
    for (int q = 0; q < 16; ++q) {
        const float4 w = Wr[q];
        #pragma unroll
        for (int r = 0; r < 8; ++r) {
            const float4 x = xs[(r0+r)*16 + q];   // wave-uniform broadcasts
            acc[r] += x.x*w.x + x.y*w.y + x.z*w.z + x.w*w.w;
        }
    }

    const int vbase = row0 + r0;
    #pragma unroll
    for (int r = 0; r < 8; ++r) xl[(vbase+r)*DD + lane] = acc[r];

    const float ai  = att_i[lane];
    const float aj  = att_j[lane];
    const float aei = att_em_i[lane];
    const float aej = att_em_j[lane];
    #pragma unroll
    for (int r = 0; r < 8; ++r) {
        const int v = vbase + r;
        const int nloc = v & (NN - 1);
        const float er = emb[nloc*DD + lane];   // coalesced 256B
        float pi = acc[r] * ai + er * aei;      // fold ei before reduce
        float pj = acc[r] * aj + er * aej;
        #pragma unroll
        for (int m = 32; m > 0; m >>= 1) {
            pi += __shfl_xor(pi, m);
            pj += __shfl_xor(pj, m);
        }
        if (lane == 0) { si[v] = pi; sj[v] = pj; }
    }
}

// ---------------------------------------------------------------------------
// K3: one wave per target. Softmax (lane=edge), then alpha transposed via a
// per-wave LDS table (1 ds_write + 9 ds_read replaces 18 bpermutes; same-wave
// DS ordering, no barrier) and gather offsets recomputed from the L2-hot
// topk row. Batched float4 gather (MLP), butterfly reduce, folded-BN
// epilogue. XCD swizzle kept. Invalid edges have alpha=0 -> offsets unmasked.
// ---------------------------------------------------------------------------
__global__ void k3_agg(const float* __restrict__ xl, const float* __restrict__ si,
                       const float* __restrict__ sj, const int* __restrict__ topk,
                       const float* __restrict__ emb,
                       const float* __restrict__ epi,
                       const float* __restrict__ outW, const float* __restrict__ outb,
                       float* __restrict__ out) {
    __shared__ float alS[4][64];             // per-wave alpha table (33 used)
    const int t = threadIdx.x;
    const int lane = t & 63;
    const int wave = t >> 6;
    const int bid = blockIdx.x;              // 8192 blocks
    const int xcd = bid & 7;
    const int ixc = bid >> 3;                // 0..1023
    const int b   = xcd + 8 * (ixc >> 7);    // batch 0..63, b%8 == xcd
    const int i   = ((ixc & 127) << 2) + wave;
    const int tgt = b * NN + i;

    // --- phase 1: lane k (0..32) = edge ---
    const bool isedge = (lane <= KK);
    int tk = i;
    bool valid = true;
    if (lane < KK) { tk = topk[i*KK + lane]; valid = (tk != i); }
    const int srcg = b * NN + tk;

    float a;
    if (isedge) {
        a = si[tgt] + sj[srcg];
        a = (a >= 0.f) ? a : NEG_SLOPE * a;   // leaky_relu
        if (!valid) a = NEG_INF_A;            // mask AFTER leaky (matches ref)
    } else {
        a = -3.0e38f;
    }

    float amax = a;
    #pragma unroll
    for (int m = 32; m > 0; m >>= 1) amax = fmaxf(amax, __shfl_xor(amax, m));

    float ex = (isedge && valid) ? __expf(a - amax) : 0.f;
    float denom = ex;
    #pragma unroll
    for (int m = 32; m > 0; m >>= 1) denom += __shfl_xor(denom, m);
    const float alpha = ex * __builtin_amdgcn_rcpf(denom);

    if (lane <= KK) alS[wave][lane] = alpha;  // per-wave table (no barrier:
                                              // same wave reads it below)

    // --- phase 2: batched float4 gather, lane = (e4, c4) ---
    const int c4 = lane & 15;
    const int e4 = lane >> 4;
    const float4* xl4 = (const float4*)xl;

    float al[9];
    int   off[9];
    #pragma unroll
    for (int m = 0; m < 8; ++m) {
        const int kk = 4*m + e4;
        al[m]  = alS[wave][kk];              // 4-addr LDS broadcast
        off[m] = (b*NN + topk[i*KK + kk])*16 + c4;   // L2-hot row reload
    }
    al[8]  = (e4 == 0) ? alS[wave][KK] : 0.f;        // self loop on group 0
    off[8] = tgt*16 + c4;

    float4 xv[9];
    #pragma unroll
    for (int m = 0; m < 9; ++m) xv[m] = xl4[off[m]];  // 9 loads in flight

    float4 acc = make_float4(0.f, 0.f, 0.f, 0.f);
    #pragma unroll
    for (int m = 0; m < 9; ++m) {
        acc.x += al[m]*xv[m].x; acc.y += al[m]*xv[m].y;
        acc.z += al[m]*xv[m].z; acc.w += al[m]*xv[m].w;
    }

    #pragma unroll
    for (int m = 16; m <= 32; m <<= 1) {
        acc.x += __shfl_xor(acc.x, m);
        acc.y += __shfl_xor(acc.y, m);
        acc.z += __shfl_xor(acc.z, m);
        acc.w += __shfl_xor(acc.w, m);
    }

    const float4* epi4 = (const float4*)epi;
    const float4 s1 = epi4[c4];
    const float4 B1 = epi4[16 + c4];
    const float4 so = epi4[32 + c4];
    const float4 Bo = epi4[48 + c4];
    const float4 em = ((const float4*)emb)[i*16 + c4];
    const float4 w4 = ((const float4*)outW)[c4];
    float4 h;
    h.x = fmaxf(acc.x*s1.x + B1.x, 0.f) * em.x;
    h.y = fmaxf(acc.y*s1.y + B1.y, 0.f) * em.y;
    h.z = fmaxf(acc.z*s1.z + B1.z, 0.f) * em.z;
    h.w = fmaxf(acc.w*s1.w + B1.w, 0.f) * em.w;
    h.x = fmaxf(h.x*so.x + Bo.x, 0.f);
    h.y = fmaxf(h.y*so.y + Bo.y, 0.f);
    h.z = fmaxf(h.z*so.z + Bo.z, 0.f);
    h.w = fmaxf(h.w*so.w + Bo.w, 0.f);
    float p = h.x*w4.x + h.y*w4.y + h.z*w4.z + h.w*w4.w;
    p += __shfl_xor(p, 1);
    p += __shfl_xor(p, 2);
    p += __shfl_xor(p, 4);
    p += __shfl_xor(p, 8);
    if (lane == 0) out[tgt] = p + outb[0];
}

// ---------------------------------------------------------------------------
extern "C" void kernel_launch(void* const* d_in, const int* in_sizes, int n_in,
                              void* d_out, int out_size, void* d_ws, size_t ws_size,
                              hipStream_t stream) {
    (void)in_sizes; (void)n_in; (void)out_size; (void)ws_size;
    const float* data   = (const float*)d_in[0];
    // d_in[1] = org_edge_index (int32) — unused by the reference forward
    const float* emb    = (const float*)d_in[2];
    const float* linW   = (const float*)d_in[3];
    const float* att_i  = (const float*)d_in[4];
    const float* att_j  = (const float*)d_in[5];
    const float* attemi = (const float*)d_in[6];
    const float* attemj = (const float*)d_in[7];
    const float* gbias  = (const float*)d_in[8];
    const float* g1     = (const float*)d_in[9];
    const float* b1     = (const float*)d_in[10];
    const float* m1     = (const float*)d_in[11];
    const float* v1     = (const float*)d_in[12];
    const float* go     = (const float*)d_in[13];
    const float* bo     = (const float*)d_in[14];
    const float* mo     = (const float*)d_in[15];
    const float* vo     = (const float*)d_in[16];
    const float* outW   = (const float*)d_in[17];
    const float* outb   = (const float*)d_in[18];
    float* out = (float*)d_out;

    // Workspace layout (bytes):
    //   epi @8K (1K)  topk @16K (64K)
    //   si @80K (128K)  sj @208K (128K)
    //   xl @336K (8M) [k2->k3]  /  keys @336K (2M) [kA->kB, dead before k2]
    char* ws = (char*)d_ws;
    float* epi  = (float*)(ws + 8192);
    int*   topk = (int*)  (ws + 16384);
    float* si   = (float*)(ws + 81920);
    float* sj   = (float*)(ws + 212992);
    float* xl   = (float*)(ws + 344064);
    ull*   keys = (ull*)  (ws + 344064);

    kA_cos<<<256, 256, 0, stream>>>(emb, keys);
    kB_rank<<<NN, NN, 0, stream>>>(keys, gbias,
                                   g1, b1, m1, v1, go, bo, mo, vo,
                                   topk, epi);
    k2_lin<<<BN/32, 256, 0, stream>>>(data, linW, emb, att_i, att_j,
                                      attemi, attemj, xl, si, sj);
    k3_agg<<<BN/4, 256, 0, stream>>>(xl, si, sj, topk, emb, epi,
                                     outW, outb, out);
}